// Round 3
// baseline (6945.616 us; speedup 1.0000x reference)
//
#include <hip/hip_runtime.h>

typedef __bf16 bf16;
typedef __bf16 bf16x8 __attribute__((ext_vector_type(8)));
typedef float f32x4 __attribute__((ext_vector_type(4)));

#define T_LEN 512
#define BATCH 64
#define HID 256
#define LDA 520   // padded K-stride (bf16 elems) for A/stage
#define ZLD 68    // padded fp32 stride for z tile

// workspace layout (total ~1.0 MB)
#define CTRL_BYTES 4096
#define H1_OFF CTRL_BYTES
#define HBUF_BYTES (2 * 3 * BATCH * HID * 2)     // dir x 3-slot x B x H x 2B = 196608
#define H2_OFF (H1_OFF + HBUF_BYTES)             // 200704
#define LOG_OFF (H2_OFF + HBUF_BYTES)            // 397312
#define LOG_BYTES (T_LEN * BATCH * 5 * 4)        // 655360 (f32 logits [T][B][5])
#define ZERO_BYTES (LOG_OFF + LOG_BYTES)         // 1052672

// LDS layout (dynamic)
#define SMEM_A 66560                    // bf16 [64][LDA] (stage for Wt, then A = [x|h])
#define SMEM_Z 17408                    // fp32 [64][ZLD]
#define SMEM_C 4096                     // fp32 c-state [64][16]
#define SMEM_TAIL 576                   // fp32 bLds[64] + dwLds[80]
#define SMEM_BYTES (SMEM_A + SMEM_Z + SMEM_C + SMEM_TAIL)

__device__ inline uint4 cvt8(const float4* s) {
    float4 a = s[0], b = s[1];
    union { uint4 u; bf16 h[8]; } r;
    r.h[0] = (bf16)a.x; r.h[1] = (bf16)a.y; r.h[2] = (bf16)a.z; r.h[3] = (bf16)a.w;
    r.h[4] = (bf16)b.x; r.h[5] = (bf16)b.y; r.h[6] = (bf16)b.z; r.h[7] = (bf16)b.w;
    return r.u;
}

__global__ void __launch_bounds__(256, 1)
lstm_kernel(const int* __restrict__ tokens,
            const float* __restrict__ embed,
            const float* __restrict__ W1f, const float* __restrict__ U1f, const float* __restrict__ b1f,
            const float* __restrict__ W2f, const float* __restrict__ U2f, const float* __restrict__ b2f,
            const float* __restrict__ W1b, const float* __restrict__ U1b, const float* __restrict__ b1b,
            const float* __restrict__ W2b, const float* __restrict__ U2b, const float* __restrict__ b2b,
            const float* __restrict__ dW,
            char* __restrict__ ws)
{
    extern __shared__ char smem[];
    bf16*  Abuf  = (bf16*)smem;                              // [64][LDA]
    float* zLds  = (float*)(smem + SMEM_A);                  // [64][ZLD]
    float* cLds  = (float*)(smem + SMEM_A + SMEM_Z);         // [1024]
    float* bLds  = (float*)(smem + SMEM_A + SMEM_Z + SMEM_C);// [64]
    float* dwLds = bLds + 64;                                // [80]

    const int tid = threadIdx.x;
    const int wg  = blockIdx.x;
    const int dir = wg >> 5, layer = (wg >> 4) & 1, sub = wg & 15;

    const float *Wp, *Up, *bp;
    if (dir == 0) { if (layer == 0) { Wp=W1f; Up=U1f; bp=b1f; } else { Wp=W2f; Up=U2f; bp=b2f; } }
    else          { if (layer == 0) { Wp=W1b; Up=U1b; bp=b1b; } else { Wp=W2b; Up=U2b; bp=b2b; } }

    // ---- stage this WG's 64 gate-columns of [W;U] transposed into Abuf as bf16: Wt[col][k] ----
    {
        for (int it = 0; it < 32; ++it) {
            int idx = it * 256 + tid;            // 8192 = 512 k x 16 col-quads
            int k = idx >> 4, q4 = idx & 15;
            int g = q4 >> 2, u0 = (q4 & 3) * 4;
            const float* src = (k < 256) ? (Wp + (size_t)k * 1024 + g * 256 + sub * 16 + u0)
                                         : (Up + (size_t)(k - 256) * 1024 + g * 256 + sub * 16 + u0);
            float4 v = *(const float4*)src;
            int c0 = g * 16 + u0;
            Abuf[(c0 + 0) * LDA + k] = (bf16)v.x;
            Abuf[(c0 + 1) * LDA + k] = (bf16)v.y;
            Abuf[(c0 + 2) * LDA + k] = (bf16)v.z;
            Abuf[(c0 + 3) * LDA + k] = (bf16)v.w;
        }
        if (tid < 64) {
            int g = tid >> 4, u = tid & 15;
            bLds[tid] = bp[g * 256 + sub * 16 + u];
        }
        if (tid < 80) {
            int u = tid / 5, c = tid % 5;
            dwLds[tid] = dW[(size_t)(dir * 256 + sub * 16 + u) * 5 + c];
        }
        for (int i = tid; i < 1024; i += 256) cLds[i] = 0.f;
    }
    __syncthreads();

    // ---- pin B fragments in registers: wave covers a 32x32 quadrant of the 64x64 C tile ----
    const int wave = tid >> 6, lane = tid & 63, quad = lane >> 4, ln = lane & 15;
    const int mrow0 = (wave >> 1) * 32, ncol0 = (wave & 1) * 32;
    bf16x8 bfrag[2][16];
#pragma unroll
    for (int nt = 0; nt < 2; ++nt) {
#pragma unroll
        for (int kt = 0; kt < 16; ++kt) {
            int col = ncol0 + nt * 16 + ln;
            bfrag[nt][kt] = *(const bf16x8*)&Abuf[col * LDA + kt * 32 + quad * 8];
        }
    }
    __syncthreads();

    bf16* h1buf = (bf16*)(ws + H1_OFF) + (size_t)dir * 3 * BATCH * HID;  // [slot][64][256]
    bf16* h2buf = (bf16*)(ws + H2_OFF) + (size_t)dir * 3 * BATCH * HID;
    float* logits = (float*)(ws + LOG_OFF);                              // [t][b][5]
    unsigned* ctr = (unsigned*)ws + dir * 32;                            // 128 B apart

    for (int t = 0; t <= T_LEN; ++t) {
        const bool active = (layer == 0) ? (t < T_LEN) : (t >= 1);
        if (active) {
            const int s = (layer == 0) ? t : t - 1;   // local step of this chain
            // ---- build A = [x | h] in LDS ----
            {
                const int b = tid >> 2, q = tid & 3;
                uint4* dstx = (uint4*)&Abuf[b * LDA + q * 64];
                if (layer == 0) {
                    const int tt = dir ? (T_LEN - 1 - s) : s;
                    const int tok = tokens[b * T_LEN + tt];
                    const float4* src = (const float4*)(embed + (size_t)tok * HID + q * 64);
#pragma unroll
                    for (int j = 0; j < 8; ++j) dstx[j] = cvt8(src + j * 2);
                } else {
                    const int slot_x = t % 3;   // h1 output of L1 step t-1
                    const uint4* src = (const uint4*)(h1buf + (size_t)slot_x * BATCH * HID + b * HID + q * 64);
#pragma unroll
                    for (int j = 0; j < 8; ++j) dstx[j] = src[j];
                }
                const int slot_h = s % 3;       // own h after step s-1
                const bf16* hsrc = ((layer == 0) ? h1buf : h2buf) + (size_t)slot_h * BATCH * HID + b * HID + q * 64;
                const uint4* s4 = (const uint4*)hsrc;
                uint4* dsth = (uint4*)&Abuf[b * LDA + 256 + q * 64];
#pragma unroll
                for (int j = 0; j < 8; ++j) dsth[j] = s4[j];
            }
            __syncthreads();

            // ---- GEMM: z[64x64] = A[64x512] @ Wt^T ----
            f32x4 acc[2][2];
#pragma unroll
            for (int mi = 0; mi < 2; ++mi)
#pragma unroll
                for (int ni = 0; ni < 2; ++ni) acc[mi][ni] = (f32x4)(0.0f);
#pragma unroll
            for (int kt = 0; kt < 16; ++kt) {
                bf16x8 a0 = *(const bf16x8*)&Abuf[(mrow0 + ln) * LDA + kt * 32 + quad * 8];
                bf16x8 a1 = *(const bf16x8*)&Abuf[(mrow0 + 16 + ln) * LDA + kt * 32 + quad * 8];
                acc[0][0] = __builtin_amdgcn_mfma_f32_16x16x32_bf16(a0, bfrag[0][kt], acc[0][0], 0, 0, 0);
                acc[0][1] = __builtin_amdgcn_mfma_f32_16x16x32_bf16(a0, bfrag[1][kt], acc[0][1], 0, 0, 0);
                acc[1][0] = __builtin_amdgcn_mfma_f32_16x16x32_bf16(a1, bfrag[0][kt], acc[1][0], 0, 0, 0);
                acc[1][1] = __builtin_amdgcn_mfma_f32_16x16x32_bf16(a1, bfrag[1][kt], acc[1][1], 0, 0, 0);
            }
#pragma unroll
            for (int mi = 0; mi < 2; ++mi) {
#pragma unroll
                for (int ni = 0; ni < 2; ++ni) {
                    int row = mrow0 + mi * 16 + quad * 4;
                    int col = ncol0 + ni * 16 + ln;
#pragma unroll
                    for (int r = 0; r < 4; ++r)
                        zLds[(row + r) * ZLD + col] = acc[mi][ni][r];
                }
            }
            __syncthreads();

            // ---- gates + fused dense partial ----
            bf16* hdst = (((layer == 0) ? h1buf : h2buf)) + (size_t)((s + 1) % 3) * BATCH * HID;
#pragma unroll
            for (int r = 0; r < 4; ++r) {
                int idx = r * 256 + tid;          // = b*16 + u
                int b = idx >> 4, u = idx & 15;
                float zi = zLds[b * ZLD + u]       + bLds[u];
                float zf = zLds[b * ZLD + 16 + u]  + bLds[16 + u];
                float zg = zLds[b * ZLD + 32 + u]  + bLds[32 + u];
                float zo = zLds[b * ZLD + 48 + u]  + bLds[48 + u];
                float ig = 1.f / (1.f + __expf(-zi));
                float fg = 1.f / (1.f + __expf(-zf));
                float gg = 1.f - 2.f / (__expf(2.f * zg) + 1.f);
                float og = 1.f / (1.f + __expf(-zo));
                float cn = fg * cLds[idx] + ig * gg;
                cLds[idx] = cn;
                float hh = og * (1.f - 2.f / (__expf(2.f * cn) + 1.f));
                hdst[b * HID + sub * 16 + u] = (bf16)hh;
                if (layer == 1) {
                    const int tp = dir ? (T_LEN - 1 - s) : s;
                    float p0 = hh * dwLds[u * 5 + 0];
                    float p1 = hh * dwLds[u * 5 + 1];
                    float p2 = hh * dwLds[u * 5 + 2];
                    float p3 = hh * dwLds[u * 5 + 3];
                    float p4 = hh * dwLds[u * 5 + 4];
#pragma unroll
                    for (int m = 1; m < 16; m <<= 1) {
                        p0 += __shfl_xor(p0, m);
                        p1 += __shfl_xor(p1, m);
                        p2 += __shfl_xor(p2, m);
                        p3 += __shfl_xor(p3, m);
                        p4 += __shfl_xor(p4, m);
                    }
                    if (u == 0) {
                        float* lp = &logits[((size_t)tp * BATCH + b) * 5];
                        atomicAdd(lp + 0, p0);
                        atomicAdd(lp + 1, p1);
                        atomicAdd(lp + 2, p2);
                        atomicAdd(lp + 3, p3);
                        atomicAdd(lp + 4, p4);
                    }
                }
            }
        }

        // ---- per-direction barrier (32 WGs), explicit agent-scope fences ----
        __syncthreads();
        __builtin_amdgcn_fence(__ATOMIC_RELEASE, "agent");
        if (tid == 0) {
            __hip_atomic_fetch_add(ctr, 1u, __ATOMIC_RELAXED, __HIP_MEMORY_SCOPE_AGENT);
            unsigned target = (unsigned)(t + 1) * 32u;
            while (__hip_atomic_load(ctr, __ATOMIC_RELAXED, __HIP_MEMORY_SCOPE_AGENT) < target)
                __builtin_amdgcn_s_sleep(1);
        }
        __syncthreads();
        __builtin_amdgcn_fence(__ATOMIC_ACQUIRE, "agent");
    }
}

__global__ void __launch_bounds__(256)
softmax_kernel(const char* __restrict__ ws, const float* __restrict__ dB, float* __restrict__ out)
{
    const int gid = blockIdx.x * 256 + threadIdx.x;
    const int b = gid & 63, t = gid >> 6;
    const float* lp = (const float*)(ws + LOG_OFF) + ((size_t)t * BATCH + b) * 5;
    float l[5];
#pragma unroll
    for (int c = 0; c < 5; ++c) l[c] = lp[c] + dB[c];
    float m = l[0];
#pragma unroll
    for (int c = 1; c < 5; ++c) m = fmaxf(m, l[c]);
    float e[5], ssum = 0.f;
#pragma unroll
    for (int c = 0; c < 5; ++c) { e[c] = __expf(l[c] - m); ssum += e[c]; }
    float inv = 1.f / ssum;
    float* o = out + ((size_t)b * T_LEN + t) * 5;
#pragma unroll
    for (int c = 0; c < 5; ++c) o[c] = e[c] * inv;
}

extern "C" void kernel_launch(void* const* d_in, const int* in_sizes, int n_in,
                              void* d_out, int out_size, void* d_ws, size_t ws_size,
                              hipStream_t stream)
{
    const int*   tokens = (const int*)d_in[0];
    const float* embed  = (const float*)d_in[1];
    const float* W1f = (const float*)d_in[2],  *U1f = (const float*)d_in[3],  *b1f = (const float*)d_in[4];
    const float* W2f = (const float*)d_in[5],  *U2f = (const float*)d_in[6],  *b2f = (const float*)d_in[7];
    const float* W1b = (const float*)d_in[8],  *U1b = (const float*)d_in[9],  *b1b = (const float*)d_in[10];
    const float* W2b = (const float*)d_in[11], *U2b = (const float*)d_in[12], *b2b = (const float*)d_in[13];
    const float* dW  = (const float*)d_in[14], *dB  = (const float*)d_in[15];

    hipFuncSetAttribute(reinterpret_cast<const void*>(lstm_kernel),
                        hipFuncAttributeMaxDynamicSharedMemorySize, SMEM_BYTES);
    hipMemsetAsync(d_ws, 0, ZERO_BYTES, stream);   // zero barrier counters + h slots + logits
    lstm_kernel<<<dim3(64), dim3(256), SMEM_BYTES, stream>>>(
        tokens, embed, W1f, U1f, b1f, W2f, U2f, b2f,
        W1b, U1b, b1b, W2b, U2b, b2b, dW, (char*)d_ws);
    softmax_kernel<<<dim3(128), dim3(256), 0, stream>>>((const char*)d_ws, dB, (float*)d_out);
}